// Round 4
// baseline (200.624 us; speedup 1.0000x reference)
//
#include <hip/hip_runtime.h>
#include <stdint.h>

#define NHITS 100000
#define NOBJ  1024
#define HALF  50000
#define HALF_PAIRS 51200000u   // NHITS*NOBJ/2

// ---------------- ws layout (bytes) ----------------
// 0:   double v_att_sum
// 8:   double v_rep_sum
// 16:  double coward_sum
// 24:  double noise_sum
// 32:  ull    noise_cnt
// 40:  u32    rep_ctr        (pure repulsive candidate count)
// 48:  float  freq
// 64:  ull    packed[1024]                         (64..8256)
// 8256:   float arec[1024*16] {x[12], qa, a2, 0,0} (8256..73792)
// 73792:  float q_arr[100000]                      (73792..473792)
// 473792: float xx_arr[100000]                     (473792..873792)
// 873792: u32 list[C]  candidate pair indices f=j*1024+k

#define LIST_OFF 873792ull

__device__ inline uint32_t rotl32(uint32_t x, int n) {
    return (x << n) | (x >> (32 - n));
}

__device__ inline void threefry2x32(uint32_t k0, uint32_t k1,
                                    uint32_t x0, uint32_t x1,
                                    uint32_t& o0, uint32_t& o1) {
    uint32_t ks2 = k0 ^ k1 ^ 0x1BD11BDAu;
    x0 += k0; x1 += k1;
#define TF_ROUND(r) { x0 += x1; x1 = rotl32(x1, r); x1 ^= x0; }
    TF_ROUND(13) TF_ROUND(15) TF_ROUND(26) TF_ROUND(6)
    x0 += k1;  x1 += ks2 + 1u;
    TF_ROUND(17) TF_ROUND(29) TF_ROUND(16) TF_ROUND(24)
    x0 += ks2; x1 += k0 + 2u;
    TF_ROUND(13) TF_ROUND(15) TF_ROUND(26) TF_ROUND(6)
    x0 += k0;  x1 += k1 + 3u;
    TF_ROUND(17) TF_ROUND(29) TF_ROUND(16) TF_ROUND(24)
    x0 += k1;  x1 += ks2 + 4u;
    TF_ROUND(13) TF_ROUND(15) TF_ROUND(26) TF_ROUND(6)
    x0 += ks2; x1 += k0 + 5u;
#undef TF_ROUND
    o0 = x0; o1 = x1;
}

__device__ inline float tf_uniform(uint32_t bits) {
    return __uint_as_float((bits >> 9) | 0x3f800000u) - 1.0f;
}

__device__ inline double waveReduceD(double v) {
    for (int off = 32; off > 0; off >>= 1) v += __shfl_down(v, off, 64);
    return v;
}
__device__ inline unsigned int waveReduceU(unsigned int v) {
    for (int off = 32; off > 0; off >>= 1) v += __shfl_down(v, off, 64);
    return v;
}

#define DOT12(XA, XB, XC, A, B, C) \
    fmaf((XC).w, (C).w, fmaf((XC).z, (C).z, fmaf((XC).y, (C).y, fmaf((XC).x, (C).x, \
    fmaf((XB).w, (B).w, fmaf((XB).z, (B).z, fmaf((XB).y, (B).y, fmaf((XB).x, (B).x, \
    fmaf((XA).w, (A).w, fmaf((XA).z, (A).z, fmaf((XA).y, (A).y, (XA).x * (A).x)))))))))))

#define SS12(XA, XB, XC) DOT12(XA, XB, XC, XA, XB, XC)

// ---------------- kernels ----------------

__global__ void k_init(unsigned long long* packed, unsigned long long* hdr) {
    int t = blockIdx.x * blockDim.x + threadIdx.x;
    if (t < NOBJ) packed[t] = 0xFFFFFFFFull;
    if (t < 8)    hdr[t] = 0ull;
}

__global__ void k_hits(const float* __restrict__ beta,
                       const float* __restrict__ x,
                       const int* __restrict__ oid,
                       unsigned long long* __restrict__ packed,
                       float* __restrict__ q_arr,
                       float* __restrict__ xx_arr,
                       double* __restrict__ noise_sum,
                       unsigned long long* __restrict__ noise_cnt) {
    int j = blockIdx.x * blockDim.x + threadIdx.x;
    float nb = 0.0f;
    unsigned int nc = 0;
    if (j < NHITS) {
        float b = beta[j];
        int o = oid[j];
        float a = atanhf(b);
        float q = a * a + 0.1f;
        q_arr[j] = q;
        const float4* x4 = (const float4*)x;
        float4 A = x4[j * 3 + 0], B = x4[j * 3 + 1], C = x4[j * 3 + 2];
        xx_arr[j] = SS12(A, B, C);
        if (o > 0) {
            unsigned long long p =
                ((unsigned long long)__float_as_uint(q) << 32) |
                (unsigned long long)(0xFFFFFFFFu - (unsigned)j);
            atomicMax(&packed[o - 1], p);
        } else {
            nb = b; nc = 1;
        }
    }
    double rb = waveReduceD((double)nb);
    unsigned int rc = waveReduceU(nc);
    if ((threadIdx.x & 63) == 0) {
        if (rb != 0.0) atomicAdd(noise_sum, rb);
        if (rc)        atomicAdd(noise_cnt, (unsigned long long)rc);
    }
}

__global__ void k_alphas(const unsigned long long* __restrict__ packed,
                         const float* __restrict__ x,
                         const float* __restrict__ beta,
                         const float* __restrict__ q_arr,
                         const float* __restrict__ xx_arr,
                         float* __restrict__ arec,
                         double* __restrict__ coward_sum) {
    int k = blockIdx.x * blockDim.x + threadIdx.x;
    double c = 0.0;
    if (k < NOBJ) {
        unsigned idx = 0xFFFFFFFFu - (unsigned)(packed[k] & 0xFFFFFFFFull);
        const float4* x4 = (const float4*)x;
        float4 A = x4[idx * 3 + 0];
        float4 B = x4[idx * 3 + 1];
        float4 C = x4[idx * 3 + 2];
        float4 D;
        D.x = q_arr[idx]; D.y = xx_arr[idx]; D.z = 0.f; D.w = 0.f;
        float4* ar = (float4*)arec;
        ar[k * 4 + 0] = A;
        ar[k * 4 + 1] = B;
        ar[k * 4 + 2] = C;
        ar[k * 4 + 3] = D;
        c = 1.0 - (double)beta[idx];
    }
    double rc = waveReduceD(c);
    if ((threadIdx.x & 63) == 0) atomicAdd(coward_sum, rc);
}

// exact attractive term
__global__ void k_att(const float* __restrict__ x,
                      const int* __restrict__ oid,
                      const float* __restrict__ q_arr,
                      const float* __restrict__ xx_arr,
                      const float* __restrict__ arec,
                      double* __restrict__ v_att_sum) {
    int j = blockIdx.x * blockDim.x + threadIdx.x;
    double va = 0.0;
    if (j < NHITS) {
        int o = oid[j];
        if (o > 0) {
            int k = o - 1;
            const float4* x4 = (const float4*)x;
            float4 XA = x4[j * 3 + 0], XB = x4[j * 3 + 1], XC = x4[j * 3 + 2];
            const float4* ar = (const float4*)arec;
            float4 A = ar[k * 4 + 0], B = ar[k * 4 + 1], C = ar[k * 4 + 2], D = ar[k * 4 + 3];
            float dot = DOT12(XA, XB, XC, A, B, C);
            float d2r = fmaf(-2.0f, dot, xx_arr[j]) + D.y;
            va = (double)((q_arr[j] * D.x) * fmaxf(d2r, 0.0f));
        }
    }
    double rv = waveReduceD(va);
    if ((threadIdx.x & 63) == 0) {
        if (rv != 0.0) atomicAdd(v_att_sum, rv);
    }
}

// scan: masks in registers, count + compact candidate list
__global__ __launch_bounds__(256)
void k_scan(const float* __restrict__ x,
            const float* __restrict__ xx_arr,
            const int* __restrict__ oid,
            const float* __restrict__ arec,
            uint32_t* __restrict__ list,
            unsigned int* __restrict__ ctr,
            unsigned int cap) {
    const int tid = threadIdx.x;
    int t = blockIdx.x * 256 + tid;
    bool valid = t < HALF;
    int j0 = valid ? t : 0;
    int j1 = j0 + HALF;
    const float4* x4 = (const float4*)x;
    float4 X0a = x4[j0 * 3 + 0], X0b = x4[j0 * 3 + 1], X0c = x4[j0 * 3 + 2];
    float4 X1a = x4[j1 * 3 + 0], X1b = x4[j1 * 3 + 1], X1c = x4[j1 * 3 + 2];
    float xx0 = valid ? xx_arr[j0] : 3e9f;
    float xx1 = valid ? xx_arr[j1] : 3e9f;
    int o0 = oid[j0], o1 = oid[j1];
    const float4* ar = (const float4*)arec;
    const int kb = blockIdx.y * 128;

    uint32_t m0[4], m1[4];
#pragma unroll
    for (int g = 0; g < 4; ++g) {
        uint32_t a0 = 0, a1 = 0, bit = 1u;
        int kbase = kb + g * 32;
        for (int kk = 0; kk < 32; ++kk, bit += bit) {
            int k = kbase + kk;
            float4 A = ar[k * 4 + 0];
            float4 B = ar[k * 4 + 1];
            float4 C = ar[k * 4 + 2];
            float a2 = arec[k * 16 + 13];
            float d0 = DOT12(X0a, X0b, X0c, A, B, C);
            float d1 = DOT12(X1a, X1b, X1c, A, B, C);
            float t0 = fmaf(-2.0f, d0, xx0) + a2;
            float t1 = fmaf(-2.0f, d1, xx1) + a2;
            a0 |= (t0 < 1.0f) ? bit : 0u;
            a1 |= (t1 < 1.0f) ? bit : 0u;
        }
        m0[g] = a0; m1[g] = a1;
    }
    // clear the (single) attractive bit if it lies in this k-window
    if (valid && o0 > 0) {
        int rel = o0 - 1 - kb;
        if (rel >= 0 && rel < 128) m0[rel >> 5] &= ~(1u << (rel & 31));
    }
    if (valid && o1 > 0) {
        int rel = o1 - 1 - kb;
        if (rel >= 0 && rel < 128) m1[rel >> 5] &= ~(1u << (rel & 31));
    }

    unsigned int cnt = 0;
#pragma unroll
    for (int g = 0; g < 4; ++g)
        cnt += (unsigned)(__popc(m0[g]) + __popc(m1[g]));

    // intra-wave exclusive prefix + one atomic per wave
    unsigned int p = cnt;
#pragma unroll
    for (int off = 1; off < 64; off <<= 1) {
        unsigned int v = __shfl_up(p, off, 64);
        if ((tid & 63) >= off) p += v;
    }
    unsigned int excl = p - cnt;
    unsigned int wtotal = __shfl(p, 63, 64);
    unsigned int base = 0;
    if ((tid & 63) == 63) base = atomicAdd(ctr, p);
    base = __shfl(base, 63, 64);

    if (base + wtotal <= cap && cnt) {
        unsigned int pos = base + excl;
        uint32_t f0base = (uint32_t)j0 * NOBJ + (uint32_t)kb;
        uint32_t f1base = (uint32_t)j1 * NOBJ + (uint32_t)kb;
#pragma unroll
        for (int g = 0; g < 4; ++g) {
            uint32_t m = m0[g];
            while (m) {
                int kk = __ffs(m) - 1; m &= m - 1;
                list[pos++] = f0base + (uint32_t)(g * 32 + kk);
            }
        }
#pragma unroll
        for (int g = 0; g < 4; ++g) {
            uint32_t m = m1[g];
            while (m) {
                int kk = __ffs(m) - 1; m &= m - 1;
                list[pos++] = f1base + (uint32_t)(g * 32 + kk);
            }
        }
    }
}

__global__ void k_freq(const unsigned int* __restrict__ ctr,
                       float* __restrict__ freq) {
    unsigned int n = *ctr;
    if (n < 1u) n = 1u;
    float f = 100000.0f / (float)n;
    *freq = fminf(f, 1.0f);
}

// balanced pass over compacted candidate list
__global__ __launch_bounds__(256)
void k_rep_list(const float* __restrict__ x,
                const float* __restrict__ q_arr,
                const float* __restrict__ xx_arr,
                const float* __restrict__ arec,
                const uint32_t* __restrict__ list,
                const unsigned int* __restrict__ ctr,
                const float* __restrict__ freq_ptr,
                unsigned int cap,
                double* __restrict__ acc_out) {
    __shared__ double sacc[4];
    unsigned int n = *ctr;
    if (n > cap) return;              // overflow -> fallback kernel handles
    const float freq = *freq_ptr;
    const float4* x4 = (const float4*)x;
    const float4* ar = (const float4*)arec;
    double acc = 0.0;
    const unsigned int stride = gridDim.x * 256;
    for (unsigned int i = blockIdx.x * 256 + threadIdx.x; i < n; i += stride) {
        uint32_t f = list[i];
        uint32_t b0, b1, bits;
        if (f < HALF_PAIRS) { threefry2x32(0u, 42u, f, f + HALF_PAIRS, b0, b1); bits = b0; }
        else                { threefry2x32(0u, 42u, f - HALF_PAIRS, f, b0, b1); bits = b1; }
        float u = tf_uniform(bits);
        if (u < freq) {
            int j = (int)(f >> 10);
            int k = (int)(f & (NOBJ - 1));
            float4 XA = x4[j * 3 + 0], XB = x4[j * 3 + 1], XC = x4[j * 3 + 2];
            float4 A = ar[k * 4 + 0], B = ar[k * 4 + 1], C = ar[k * 4 + 2], D = ar[k * 4 + 3];
            float dot = DOT12(XA, XB, XC, A, B, C);
            float d2 = fmaf(-2.0f, dot, xx_arr[j]) + D.y;
            float dist = sqrtf(fmaxf(fmaxf(d2, 0.0f), 1e-12f));
            acc += (double)((q_arr[j] * D.x) * (1.0f - dist));
        }
    }
    double rv = waveReduceD(acc);
    if ((threadIdx.x & 63) == 0) sacc[threadIdx.x >> 6] = rv;
    __syncthreads();
    if (threadIdx.x == 0) {
        double s = sacc[0] + sacc[1] + sacc[2] + sacc[3];
        if (s != 0.0) atomicAdd(acc_out, s);
    }
}

// fallback (list overflow): rescan + sample in place. Early-exits otherwise.
__global__ __launch_bounds__(256)
void k_rep_fb(const float* __restrict__ x,
              const float* __restrict__ q_arr,
              const float* __restrict__ xx_arr,
              const int* __restrict__ oid,
              const float* __restrict__ arec,
              const unsigned int* __restrict__ ctr,
              unsigned int cap,
              const float* __restrict__ freq_ptr,
              double* __restrict__ acc_out) {
    if (*ctr <= cap) return;
    __shared__ double sacc[4];
    const int tid = threadIdx.x;
    int t = blockIdx.x * 256 + tid;
    bool valid = t < HALF;
    int j0 = valid ? t : 0;
    int j1 = j0 + HALF;
    const float4* x4 = (const float4*)x;
    float4 X0a = x4[j0 * 3 + 0], X0b = x4[j0 * 3 + 1], X0c = x4[j0 * 3 + 2];
    float4 X1a = x4[j1 * 3 + 0], X1b = x4[j1 * 3 + 1], X1c = x4[j1 * 3 + 2];
    float xx0 = valid ? xx_arr[j0] : 3e9f;
    float xx1 = valid ? xx_arr[j1] : 3e9f;
    int o0 = oid[j0], o1 = oid[j1];
    const float4* ar = (const float4*)arec;
    const int kb = blockIdx.y * 128;
    const float freq = *freq_ptr;

    uint32_t m0[4], m1[4];
#pragma unroll
    for (int g = 0; g < 4; ++g) {
        uint32_t a0 = 0, a1 = 0, bit = 1u;
        int kbase = kb + g * 32;
        for (int kk = 0; kk < 32; ++kk, bit += bit) {
            int k = kbase + kk;
            float4 A = ar[k * 4 + 0];
            float4 B = ar[k * 4 + 1];
            float4 C = ar[k * 4 + 2];
            float a2 = arec[k * 16 + 13];
            float d0 = DOT12(X0a, X0b, X0c, A, B, C);
            float d1 = DOT12(X1a, X1b, X1c, A, B, C);
            float t0 = fmaf(-2.0f, d0, xx0) + a2;
            float t1 = fmaf(-2.0f, d1, xx1) + a2;
            a0 |= (t0 < 1.0f) ? bit : 0u;
            a1 |= (t1 < 1.0f) ? bit : 0u;
        }
        m0[g] = a0; m1[g] = a1;
    }
    if (valid && o0 > 0) {
        int rel = o0 - 1 - kb;
        if (rel >= 0 && rel < 128) m0[rel >> 5] &= ~(1u << (rel & 31));
    }
    if (valid && o1 > 0) {
        int rel = o1 - 1 - kb;
        if (rel >= 0 && rel < 128) m1[rel >> 5] &= ~(1u << (rel & 31));
    }

    double acc = 0.0;
#define FB_SLOT(MARR, J, XA, XB, XC, XX)                                        \
    for (int g = 0; g < 4; ++g) {                                               \
        uint32_t m = MARR[g];                                                   \
        while (m) {                                                             \
            int kk = __ffs(m) - 1; m &= m - 1;                                  \
            int k = kb + g * 32 + kk;                                           \
            uint32_t f = (uint32_t)(J) * NOBJ + (uint32_t)k;                    \
            uint32_t b0_, b1_, bits;                                            \
            if (f < HALF_PAIRS) { threefry2x32(0u, 42u, f, f + HALF_PAIRS, b0_, b1_); bits = b0_; } \
            else                { threefry2x32(0u, 42u, f - HALF_PAIRS, f, b0_, b1_); bits = b1_; } \
            float u = tf_uniform(bits);                                         \
            if (u < freq) {                                                     \
                float4 A = ar[k * 4 + 0], B = ar[k * 4 + 1], C = ar[k * 4 + 2], D = ar[k * 4 + 3]; \
                float dot = DOT12(XA, XB, XC, A, B, C);                         \
                float d2 = fmaf(-2.0f, dot, XX) + D.y;                          \
                float dist = sqrtf(fmaxf(fmaxf(d2, 0.0f), 1e-12f));             \
                acc += (double)((q_arr[J] * D.x) * (1.0f - dist));              \
            }                                                                   \
        }                                                                       \
    }
    FB_SLOT(m0, j0, X0a, X0b, X0c, xx0)
    FB_SLOT(m1, j1, X1a, X1b, X1c, xx1)
#undef FB_SLOT

    double rv = waveReduceD(acc);
    if ((tid & 63) == 0) sacc[tid >> 6] = rv;
    __syncthreads();
    if (tid == 0) {
        double s = sacc[0] + sacc[1] + sacc[2] + sacc[3];
        if (s != 0.0) atomicAdd(acc_out, s);
    }
}

__global__ void k_final(const double* __restrict__ accs,
                        const unsigned long long* __restrict__ noise_cnt,
                        const float* __restrict__ freq,
                        float* __restrict__ out) {
    double v_att = accs[0] / (double)NHITS;
    double v_rep = accs[1] / (double)(*freq) / (double)NHITS;
    double l_cow = accs[2] / (double)NOBJ;
    unsigned long long nc = *noise_cnt;
    if (nc < 1ull) nc = 1ull;
    double l_noise = accs[3] / ((double)nc + 1e-9);
    double loss = v_att + v_rep + l_cow + 0.1 * l_noise;
    out[0] = (float)v_att;
    out[1] = (float)v_rep;
    out[2] = (float)l_cow;
    out[3] = (float)l_noise;
    out[4] = (float)loss;
}

// ---------------- launcher ----------------

extern "C" void kernel_launch(void* const* d_in, const int* in_sizes, int n_in,
                              void* d_out, int out_size, void* d_ws, size_t ws_size,
                              hipStream_t stream) {
    const float* beta = (const float*)d_in[0];
    const float* x    = (const float*)d_in[1];
    const int*   oid  = (const int*)d_in[2];
    float* out = (float*)d_out;

    char* ws = (char*)d_ws;
    double* v_att_sum = (double*)(ws + 0);
    double* v_rep_sum = (double*)(ws + 8);
    double* coward_sum = (double*)(ws + 16);
    double* noise_sum = (double*)(ws + 24);
    unsigned long long* noise_cnt = (unsigned long long*)(ws + 32);
    unsigned int* rep_ctr = (unsigned int*)(ws + 40);
    float* freq = (float*)(ws + 48);
    unsigned long long* packed = (unsigned long long*)(ws + 64);
    float* arec = (float*)(ws + 8256);
    float* q_arr = (float*)(ws + 73792);
    float* xx_arr = (float*)(ws + 473792);
    uint32_t* list = (uint32_t*)(ws + LIST_OFF);

    unsigned int cap = 0;
    if (ws_size > LIST_OFF + 4) {
        size_t c = (ws_size - LIST_OFF) / 4;
        cap = (c > 0xF0000000ull) ? 0xF0000000u : (unsigned int)c;
    }

    k_init<<<4, 256, 0, stream>>>(packed, (unsigned long long*)ws);
    k_hits<<<(NHITS + 255) / 256, 256, 0, stream>>>(beta, x, oid, packed,
                                                    q_arr, xx_arr,
                                                    noise_sum, noise_cnt);
    k_alphas<<<4, 256, 0, stream>>>(packed, x, beta, q_arr, xx_arr,
                                    arec, coward_sum);

    dim3 gs((HALF + 255) / 256, 8);
    k_scan<<<gs, 256, 0, stream>>>(x, xx_arr, oid, arec, list, rep_ctr, cap);

    k_att<<<(NHITS + 255) / 256, 256, 0, stream>>>(x, oid, q_arr, xx_arr,
                                                   arec, v_att_sum);
    k_freq<<<1, 1, 0, stream>>>(rep_ctr, freq);

    k_rep_list<<<2048, 256, 0, stream>>>(x, q_arr, xx_arr, arec, list,
                                         rep_ctr, freq, cap, v_rep_sum);
    k_rep_fb<<<gs, 256, 0, stream>>>(x, q_arr, xx_arr, oid, arec,
                                     rep_ctr, cap, freq, v_rep_sum);

    k_final<<<1, 1, 0, stream>>>((double*)ws, noise_cnt, freq, out);
}